// Round 3
// baseline (634.458 us; speedup 1.0000x reference)
//
#include <hip/hip_runtime.h>
#include <hip/hip_bf16.h>
#include <math.h>

typedef __hip_bfloat16 bf16;
typedef __attribute__((ext_vector_type(8))) short short8;
typedef __attribute__((ext_vector_type(4))) short short4v;
typedef __attribute__((ext_vector_type(4))) float floatx4;

#define N_TOK 2048
#define DM    1024
#define NH    16
#define NKV   4
#define DH    64
#define NE    8
#define FF    2048
#define CH    64
#define QSCL  0.18033688011112042f   /* (1/sqrt(64)) * log2(e) */

__device__ __forceinline__ float b2f(bf16 x) { return __bfloat162float(x); }
__device__ __forceinline__ bf16  f2b(float x) { return __float2bfloat16(x); }
__device__ __forceinline__ short f2s(float x) { bf16 t = __float2bfloat16(x); return *(short*)&t; }

#define MFMA16(a, b, c) __builtin_amdgcn_mfma_f32_16x16x32_bf16(a, b, c, 0, 0, 0)

// async global->LDS, 16B per lane; LDS dest = wave-uniform base + lane*16
#define GLL16(g, l) __builtin_amdgcn_global_load_lds( \
    (const __attribute__((address_space(1))) void*)(g), \
    (__attribute__((address_space(3))) void*)(l), 16, 0, 0)

__device__ __forceinline__ float blockReduceSum256(float v) {
    __shared__ float tmp[4];
    #pragma unroll
    for (int m = 1; m < 64; m <<= 1) v += __shfl_xor(v, m, 64);
    if ((threadIdx.x & 63) == 0) tmp[threadIdx.x >> 6] = v;
    __syncthreads();
    float r = tmp[0] + tmp[1] + tmp[2] + tmp[3];
    __syncthreads();
    return r;
}

// ---------------- merged transpose: fp32 KxN -> bf16 NxK -------------------
// Tile: 64 n-cols x TK k-rows. Write side is the DRAM-efficiency driver:
// each dst row gets a TK*2-byte (512B at TK=256) contiguous chunk, and each
// readout round is one fully-coalesced 512B segment per n. Reads are 256B/row
// but nt-major grid order lets ~32 concurrent blocks aggregate full rows.
// LDS: short8-packed stores (8 k gathered in regs -> 1 ds_write_b128 per n),
// XOR-16B swizzle for conflict-spread readout.
struct TEnt {
    const float* src; bf16* dst;
    long sstride, dstride;
    int sN, ldk, tN, tilesPer, start;
};
struct TTab { TEnt t[13]; };

template <int TK>
__global__ __launch_bounds__(256) void k_transpose_all(TTab tab, int base,
                                                       int* counts, int* fill) {
    if (base == 0 && blockIdx.x == 0 && threadIdx.x < NE) {
        counts[threadIdx.x] = 0;
        fill[threadIdx.x] = 0;
    }
    int b = blockIdx.x + base;
    int wi = 0;
    #pragma unroll
    for (int i = 1; i < 13; i++) if (b >= tab.t[i].start) wi = i;
    const TEnt& w = tab.t[wi];
    int local = b - w.start;
    int e = local / w.tilesPer; local -= e * w.tilesPer;
    int kt = local / w.tN, nt = local - kt * w.tN;
    const float* s = w.src + (long)e * w.sstride + (long)(kt * TK) * w.sN + nt * 64;
    bf16* d = w.dst + (long)e * w.dstride + (long)(nt * 64) * w.ldk + kt * TK;

    __shared__ short t16[64 * TK];
    int tid = threadIdx.x;
    int c4 = (tid & 15) * 4;

    #pragma unroll
    for (int j = 0; j < (TK / 8 + 15) / 16; j++) {
        int kk8 = 8 * ((tid >> 4) + 16 * j);
        if (kk8 < TK) {
            float4 rr[8];
            #pragma unroll
            for (int t = 0; t < 8; t++)
                rr[t] = *(const float4*)(s + (long)(kk8 + t) * w.sN + c4);
            #pragma unroll
            for (int q = 0; q < 4; q++) {
                int n = c4 + q;
                int ks = kk8 ^ ((n & 7) << 3);
                short8 o;
                #pragma unroll
                for (int t = 0; t < 8; t++) o[t] = f2s(((const float*)&rr[t])[q]);
                *(short8*)&t16[n * TK + ks] = o;
            }
        }
    }
    __syncthreads();
    const int cpr = TK / 8;   // 16B chunks per dst row
    #pragma unroll
    for (int rnd = 0; rnd < TK / 32; rnd++) {
        int id = tid + rnd * 256;
        int n = id / cpr;
        int kc = (id % cpr) * 8;
        int ks = kc ^ ((n & 7) << 3);
        short8 o = *(const short8*)&t16[n * TK + ks];
        *(short8*)(d + (long)n * w.ldk + kc) = o;
    }
}

// ---------------- fused: rmsnorm(hidden)->catA[:,0:1024], cvt mu/vel -------
__global__ __launch_bounds__(256) void k_prep(
    const float* __restrict__ hidden, const float* __restrict__ ln1_w,
    const float* __restrict__ mu_prev, const float* __restrict__ velocity,
    bf16* __restrict__ catA, bf16* __restrict__ ctrlA)
{
    int n = blockIdx.x, tid = threadIdx.x;
    float ss = 0.f, vals[4];
    #pragma unroll
    for (int i = 0; i < 4; i++) {
        int c = tid + i * 256;
        vals[i] = hidden[(long)n * DM + c];
        ss += vals[i] * vals[i];
        catA[(long)n * 2048 + 1024 + c] = f2b(mu_prev[(long)n * DM + c]);
        ctrlA[(long)n * 2048 + 1024 + c] = f2b(velocity[(long)n * DM + c]);
    }
    float tot = blockReduceSum256(ss);
    float r = rsqrtf(tot / (float)DM + 1e-6f);
    #pragma unroll
    for (int i = 0; i < 4; i++) {
        int c = tid + i * 256;
        catA[(long)n * 2048 + c] = f2b(vals[i] * r * ln1_w[c]);
    }
}

// ---------------- generic 128x128 MFMA GEMM, bf16 A (MxK) x bf16 B^T (NxK) -
#define GEMM_WRITE  1
#define GEMM_BIAS   2
#define GEMM_WRITEB 4
#define GEMM_DOWN   8

__global__ __launch_bounds__(256) void k_gemm(
    const bf16* __restrict__ A, int lda,
    const bf16* __restrict__ Bt, int ldb, long strideBe,
    float* __restrict__ C, int ldc,
    const float* __restrict__ bias,
    bf16* __restrict__ Cb, int ldcb,
    int K, int flags,
    int nsplit, long strideKc,
    const int* __restrict__ grp_cnt,
    const int* __restrict__ perm,
    float* __restrict__ outp)
{
    __shared__ __align__(16) short As[128 * 32];
    __shared__ __align__(16) short Bs[128 * 32];
    int tid = threadIdx.x;
    int e = blockIdx.z, kc = 0;
    if (nsplit > 1) { e = blockIdx.z / nsplit; kc = blockIdx.z % nsplit; }
    int rowBase, rowsValid;
    const bf16* Bp = Bt;
    if (grp_cnt) {
        int r0 = 0;
        #pragma unroll
        for (int i = 0; i < NE; i++) r0 += (i < e) ? grp_cnt[i] : 0;
        int r1 = r0 + grp_cnt[e];
        int rt = blockIdx.y * 128;
        rowsValid = (r1 - r0) - rt;
        if (rowsValid <= 0) return;
        if (rowsValid > 128) rowsValid = 128;
        rowBase = r0 + rt;
        Bp = Bt + (long)e * strideBe;
    } else {
        rowBase = blockIdx.y * 128;
        rowsValid = 128;
    }
    int n0 = blockIdx.x * 128;
    int Kc = K / nsplit;
    int kbeg = kc * Kc, kend = kbeg + Kc;

    floatx4 acc[4][4];
    #pragma unroll
    for (int i = 0; i < 4; i++)
        #pragma unroll
        for (int j = 0; j < 4; j++) acc[i][j] = (floatx4){0.f, 0.f, 0.f, 0.f};

    int wave = tid >> 6, lane = tid & 63;
    int wm = (wave >> 1) * 64, wn = (wave & 1) * 64;
    int lrow = lane & 15, quad = lane >> 4;

    int c0 = wave * 2;
    int srow0 = c0 * 16 + (lane >> 2);
    int srow1 = (c0 + 1) * 16 + (lane >> 2);
    int skoff = (lane & 3) * 8;
    short* ldsA0 = As + c0 * 512;
    short* ldsA1 = As + (c0 + 1) * 512;
    short* ldsB0 = Bs + c0 * 512;
    short* ldsB1 = Bs + (c0 + 1) * 512;

    for (int k0 = kbeg; k0 < kend; k0 += 32) {
        if (srow0 < rowsValid) GLL16(A + (long)(rowBase + srow0) * lda + k0 + skoff, ldsA0);
        if (srow1 < rowsValid) GLL16(A + (long)(rowBase + srow1) * lda + k0 + skoff, ldsA1);
        GLL16(Bp + (long)(n0 + srow0) * ldb + k0 + skoff, ldsB0);
        GLL16(Bp + (long)(n0 + srow1) * ldb + k0 + skoff, ldsB1);
        __syncthreads();
        short8 af[4], bfr[4];
        #pragma unroll
        for (int mi = 0; mi < 4; mi++)
            af[mi] = *(const short8*)(&As[(wm + mi * 16 + lrow) * 32 + quad * 8]);
        #pragma unroll
        for (int ni = 0; ni < 4; ni++)
            bfr[ni] = *(const short8*)(&Bs[(wn + ni * 16 + lrow) * 32 + quad * 8]);
        #pragma unroll
        for (int mi = 0; mi < 4; mi++)
            #pragma unroll
            for (int ni = 0; ni < 4; ni++)
                acc[mi][ni] = MFMA16(af[mi], bfr[ni], acc[mi][ni]);
        __syncthreads();
    }

    #pragma unroll
    for (int mi = 0; mi < 4; mi++) {
        #pragma unroll
        for (int ni = 0; ni < 4; ni++) {
            #pragma unroll
            for (int r = 0; r < 4; r++) {
                int rl = wm + mi * 16 + quad * 4 + r;
                if (rl >= rowsValid) continue;
                int grow = rowBase + rl;
                int gcol = n0 + wn + ni * 16 + lrow;
                float v = acc[mi][ni][r];
                if (nsplit > 1) {
                    C[kc * strideKc + (long)grow * ldc + gcol] = v;
                    continue;
                }
                if (flags & GEMM_BIAS) v += bias[gcol];
                if (flags & GEMM_DOWN) {
                    int tok = perm[grow];
                    float* o = &outp[(long)tok * ldc + gcol];
                    *o = *o + v;
                } else {
                    if (flags & GEMM_WRITE) C[(long)grow * ldc + gcol] = v;
                    if (flags & GEMM_WRITEB) Cb[(long)grow * ldcb + gcol] = f2b(v);
                }
            }
        }
    }
}

// ---------------- split-K reduce: wo (o_f fp32 + ctrlA bf16) ---------------
__global__ __launch_bounds__(256) void k_red_wo(const float* __restrict__ p,
                                                float* __restrict__ o_f,
                                                bf16* __restrict__ ctrlA) {
    int n = blockIdx.x, tid = threadIdx.x;
    #pragma unroll
    for (int i = 0; i < 4; i++) {
        int c = tid + i * 256;
        float v = p[(long)n * DM + c] + p[(long)N_TOK * DM + (long)n * DM + c];
        o_f[(long)n * DM + c] = v;
        ctrlA[(long)n * 2048 + c] = f2b(v);
    }
}

// ---------------- split-K reduce: down (4 partials, perm scatter, +=) ------
__global__ __launch_bounds__(256) void k_red_down(const float* __restrict__ p,
                                                  const int* __restrict__ perm,
                                                  float* __restrict__ out0) {
    int r = blockIdx.x, tid = threadIdx.x;
    int tok = perm[r];
    #pragma unroll
    for (int i = 0; i < 4; i++) {
        int c = tid + i * 256;
        long idx = (long)r * DM + c;
        float v = p[idx] + p[(long)N_TOK * DM + idx] +
                  p[(long)2 * N_TOK * DM + idx] + p[(long)3 * N_TOK * DM + idx];
        out0[(long)tok * DM + c] += v;
    }
}

// ---------------- ctrl_in GEMM: part[kc] = [o|vel] @ W_in (K-chunked) ------
__global__ __launch_bounds__(256) void k_ctrl_gemm(
    const bf16* __restrict__ A,      // ctrlA 2048 x 2048
    const bf16* __restrict__ Bt,     // ctrl_inT 64 x 2048
    float* __restrict__ part)        // [8][2048][64]
{
    __shared__ __align__(16) short As[128 * 32];
    __shared__ __align__(16) short Bs[64 * 32];
    int tid = threadIdx.x;
    int rowBase = blockIdx.x * 128;
    int kbeg = blockIdx.y * 256;
    int wave = tid >> 6, lane = tid & 63;
    int wm = wave * 32, lrow = lane & 15, quad = lane >> 4;
    int srow = lane >> 2, skoff = (lane & 3) * 8;

    floatx4 acc[2][4];
    #pragma unroll
    for (int i = 0; i < 2; i++)
        #pragma unroll
        for (int j = 0; j < 4; j++) acc[i][j] = (floatx4){0.f, 0.f, 0.f, 0.f};

    short* ldsA0 = As + (wave * 2) * 512;
    short* ldsA1 = As + (wave * 2 + 1) * 512;
    short* ldsB  = Bs + wave * 512;

    for (int k0 = kbeg; k0 < kbeg + 256; k0 += 32) {
        GLL16(A + (long)(rowBase + wave * 32 + srow) * 2048 + k0 + skoff, ldsA0);
        GLL16(A + (long)(rowBase + wave * 32 + 16 + srow) * 2048 + k0 + skoff, ldsA1);
        GLL16(Bt + (long)(wave * 16 + srow) * 2048 + k0 + skoff, ldsB);
        __syncthreads();
        short8 af[2], bfr[4];
        af[0] = *(const short8*)(&As[(wm + lrow) * 32 + quad * 8]);
        af[1] = *(const short8*)(&As[(wm + 16 + lrow) * 32 + quad * 8]);
        #pragma unroll
        for (int ni = 0; ni < 4; ni++)
            bfr[ni] = *(const short8*)(&Bs[(ni * 16 + lrow) * 32 + quad * 8]);
        #pragma unroll
        for (int mi = 0; mi < 2; mi++)
            #pragma unroll
            for (int ni = 0; ni < 4; ni++)
                acc[mi][ni] = MFMA16(af[mi], bfr[ni], acc[mi][ni]);
        __syncthreads();
    }
    #pragma unroll
    for (int mi = 0; mi < 2; mi++)
        #pragma unroll
        for (int ni = 0; ni < 4; ni++)
            #pragma unroll
            for (int r = 0; r < 4; r++) {
                int grow = rowBase + wm + mi * 16 + quad * 4 + r;
                part[((long)blockIdx.y * N_TOK + grow) * 64 + ni * 16 + lrow] = acc[mi][ni][r];
            }
}

__global__ __launch_bounds__(256) void k_silu_ctrl(const float* __restrict__ part,
                                                   const float* __restrict__ b,
                                                   bf16* __restrict__ out) {
    int i4 = (blockIdx.x * 256 + threadIdx.x) * 4;   // over 2048*64
    float4 a = *(const float4*)(b + (i4 & 63));
    #pragma unroll
    for (int kc = 0; kc < 8; kc++) {
        float4 p = *(const float4*)(part + (long)kc * (N_TOK * 64) + i4);
        a.x += p.x; a.y += p.y; a.z += p.z; a.w += p.w;
    }
    short4v o;
    o[0] = f2s(a.x / (1.f + __expf(-a.x)));
    o[1] = f2s(a.y / (1.f + __expf(-a.y)));
    o[2] = f2s(a.z / (1.f + __expf(-a.z)));
    o[3] = f2s(a.w / (1.f + __expf(-a.w)));
    *(short4v*)(out + i4) = o;
}

// ---------------- qk norm + rope + split (sums 2 K-split partials) ---------
// NOTE: Q is pre-scaled by QSCL (softmax runs in exp2 domain downstream).
__global__ __launch_bounds__(256) void k_qkv_post(
    const float* __restrict__ qkvp, const int* __restrict__ positions,
    const float* __restrict__ qnw, const float* __restrict__ knw,
    bf16* __restrict__ q, bf16* __restrict__ k, bf16* __restrict__ v)
{
    int n = blockIdx.x;
    int wave = threadIdx.x >> 6, lane = threadIdx.x & 63;
    float pos = (float)positions[n];
    int i = lane & 31;
    float invf = exp2f(-(float)(2 * i) * (13.287712379549449f / 64.f));
    float ang = pos * invf;
    float c = cosf(ang), s = sinf(ang);

    #pragma unroll
    for (int si = 0; si < 6; si++) {
        int slot = wave + si * 4;  // 0..23
        long base = (long)n * 1536 +
                    (slot < 16 ? slot * 64
                               : (slot < 20 ? 1024 + (slot - 16) * 64
                                            : 1280 + (slot - 20) * 64));
        float val = qkvp[base + lane] + qkvp[(long)N_TOK * 1536 + base + lane];
        if (slot < 20) {
            float ss = val * val;
            #pragma unroll
            for (int m = 1; m < 64; m <<= 1) ss += __shfl_xor(ss, m, 64);
            float r = rsqrtf(ss / 64.f + 1e-6f);
            float wn = (slot < 16 ? qnw[lane] : knw[lane]);
            float xn = val * r * wn;
            float partner = __shfl_xor(xn, 32, 64);
            float out = (lane < 32) ? (xn * c - partner * s) : (xn * c + partner * s);
            if (slot < 16) q[((long)n * NH + slot) * 64 + lane] = f2b(out * QSCL);
            else           k[((long)n * NKV + (slot - 16)) * 64 + lane] = f2b(out);
        } else {
            v[((long)n * NKV + (slot - 20)) * 64 + lane] = f2b(val);
        }
    }
}

// ---------------- V transpose: v[n][kv][d] -> vt[kv*64+d][n] ---------------
__global__ __launch_bounds__(256) void k_vt(const bf16* __restrict__ v,
                                            bf16* __restrict__ vt) {
    __shared__ short tile[64][65];
    int kv = blockIdx.z, n0 = blockIdx.x * 64;
    int tid = threadIdx.x;
    int c = tid & 63, r4 = tid >> 6;
    const short* vs = (const short*)v;
    #pragma unroll
    for (int i = 0; i < 16; i++) {
        int r = i * 4 + r4;
        tile[r][c] = vs[(long)(n0 + r) * 256 + kv * 64 + c];
    }
    __syncthreads();
    #pragma unroll
    for (int i = 0; i < 16; i++) {
        int d = i * 4 + r4;
        ((short*)vt)[(long)(kv * 64 + d) * 2048 + n0 + c] = tile[c][d];
    }
}

// ---------------- flash attention, KV-split 4 (partials) -------------------
__device__ __forceinline__ int lds_idx(int row, int col_sh) {
    int byteoff = col_sh * 2;
    byteoff ^= (row & 7) << 4;            // swizzle 16B blocks within row
    return row * 64 + (byteoff >> 1);
}

__global__ __launch_bounds__(256) void k_attn(
    const bf16* __restrict__ q, const bf16* __restrict__ k,
    const bf16* __restrict__ vt,
    float* __restrict__ opart, float2* __restrict__ ml)
{
    const int h = blockIdx.y;
    const int qbase = blockIdx.x * 64;
    const int z = blockIdx.z;
    const int kvh = h >> 2;
    __shared__ __align__(16) short Ks[64 * 64];
    __shared__ __align__(16) short Vt[64 * 64];
    __shared__ __align__(16) short Ps[64 * 64];
    int tid = threadIdx.x, wave = tid >> 6, lane = tid & 63;
    int lrow = lane & 15, quad = lane >> 4;

    const bf16* qp = q + ((long)(qbase + wave * 16 + lrow) * NH + h) * 64;
    short8 aq0 = *(const short8*)(qp + quad * 8);
    short8 aq1 = *(const short8*)(qp + 32 + quad * 8);

    short8 bones;
    #pragma unroll
    for (int j = 0; j < 8; j++) bones[j] = (short)0x3F80;  // bf16 1.0

    const int lin0 = tid, lin1 = tid + 256;
    const int sr0 = lin0 >> 3, sc0 = (lin0 & 7) * 8;
    const int sr1 = lin1 >> 3, sc1 = (lin1 & 7) * 8;
    const int wi0 = lds_idx(sr0, sc0), wi1 = lds_idx(sr1, sc1);

    const int kt0 = z * (N_TOK / 4);
    const bf16* kg0 = k + ((long)(kt0 + sr0) * NKV + kvh) * 64 + sc0;
    const bf16* kg1 = k + ((long)(kt0 + sr1) * NKV + kvh) * 64 + sc1;
    const bf16* vg0 = vt + (long)(kvh * 64 + sr0) * 2048 + kt0 + sc0;
    const bf16* vg1 = vt + (long)(kvh * 64 + sr1) * 2048 + kt0 + sc1;

    *(short8*)&Ks[wi0] = *(const short8*)kg0;
    *(short8*)&Ks[wi1] = *(const short8*)kg1;
    *(short8*)&Vt[wi0] = *(const short8*)vg0;
    *(short8*)&Vt[wi1] = *(const short8*)vg1;

    float m_i[4];
    floatx4 lacc = (floatx4){0.f, 0.f, 0.f, 0.f};
    floatx4 oacc[4];
    #pragma unroll
    for (int r = 0; r < 4; r++) m_i[r] = -1e30f;
    #pragma unroll
    for (int di = 0; di < 4; di++) oacc[di] = (floatx4){0.f, 0.f, 0.f, 0.f};
    __syncthreads();

    const int NT = (N_TOK / 4) / 64;   // 8 tiles per block
    for (int t = 0; t < NT; t++) {
        bool pf = (t + 1 < NT);
        short8 nk0, nk1, nv0, nv1;
        if (pf) {
            long ko = (long)(t + 1) * (64 * NKV * 64);
            int  vo = (t + 1) * 64;
            nk0 = *(const short8*)(kg0 + ko);
            nk1 = *(const short8*)(kg1 + ko);
            nv0 = *(const short8*)(vg0 + vo);
            nv1 = *(const short8*)(vg1 + vo);
        }

        floatx4 sv[4];
        __builtin_amdgcn_s_setprio(1);
        #pragma unroll
        for (int kn = 0; kn < 4; kn++) {
            short8 b0 = *(const short8*)&Ks[lds_idx(kn * 16 + lrow, quad * 8)];
            short8 b1 = *(const short8*)&Ks[lds_idx(kn * 16 + lrow, 32 + quad * 8)];
            floatx4 tt = (floatx4){0.f, 0.f, 0.f, 0.f};
            tt = MFMA16(aq0, b0, tt);
            tt = MFMA16(aq1, b1, tt);
            sv[kn] = tt;
        }
        __builtin_amdgcn_s_setprio(0);

        float mx[4];
        #pragma unroll
        for (int r = 0; r < 4; r++) {
            float m0 = fmaxf(fmaxf(sv[0][r], sv[1][r]), fmaxf(sv[2][r], sv[3][r]));
            #pragma unroll
            for (int msk = 1; msk < 16; msk <<= 1) m0 = fmaxf(m0, __shfl_xor(m0, msk, 64));
            mx[r] = m0;
        }
        int ok = (mx[0] <= m_i[0] + 8.f) & (mx[1] <= m_i[1] + 8.f) &
                 (mx[2] <= m_i[2] + 8.f) & (mx[3] <= m_i[3] + 8.f);
        if (!__all(ok)) {
            #pragma unroll
            for (int r = 0; r < 4; r++) {
                float mn = fmaxf(m_i[r], mx[r]);
                float al = exp2f(m_i[r] - mn);
                m_i[r] = mn;
                lacc[r] *= al;
                #pragma unroll
                for (int di = 0; di < 4; di++) oacc[di][r] *= al;
            }
        }
        #pragma unroll
        for (int kn = 0; kn < 4; kn++)
            #pragma unroll
            for (int r = 0; r < 4; r++)
                sv[kn][r] = exp2f(sv[kn][r] - m_i[r]);

        #pragma unroll
        for (int kn = 0; kn < 4; kn++)
            #pragma unroll
            for (int r = 0; r < 4; r++)
                Ps[lds_idx(wave * 16 + quad * 4 + r, kn * 16 + lrow)] = f2s(sv[kn][r]);
        __syncthreads();

        short8 ap0 = *(const short8*)&Ps[lds_idx(wave * 16 + lrow, quad * 8)];
        short8 ap1 = *(const short8*)&Ps[lds_idx(wave * 16 + lrow, 32 + quad * 8)];
        __builtin_amdgcn_s_setprio(1);
        lacc = MFMA16(ap0, bones, lacc);
        lacc = MFMA16(ap1, bones, lacc);
        #pragma unroll
        for (int di = 0; di < 4; di++) {
            short8 bv0 = *(const short8*)&Vt[lds_idx(di * 16 + lrow, quad * 8)];
            short8 bv1 = *(const short8*)&Vt[lds_idx(di * 16 + lrow, 32 + quad * 8)];
            oacc[di] = MFMA16(ap0, bv0, oacc[di]);
            oacc[di] = MFMA16(ap1, bv1, oacc[di]);
        }
        __builtin_amdgcn_s_setprio(0);
        __syncthreads();

        if (pf) {
            *(short8*)&Ks[wi0] = nk0;
            *(short8*)&Ks[wi1] = nk1;
            *(short8*)&Vt[wi0] = nv0;
            *(short8*)&Vt[wi1] = nv1;
            __syncthreads();
        }
    }

    #pragma unroll
    for (int di = 0; di < 4; di++)
        #pragma unroll
        for (int r = 0; r < 4; r++) {
            int n = qbase + wave * 16 + quad * 4 + r;
            opart[((long)z * N_TOK + n) * DM + h * 64 + di * 16 + lrow] = oacc[di][r];
        }
    if (lrow == 0) {
        #pragma unroll
        for (int r = 0; r < 4; r++) {
            int n = qbase + wave * 16 + quad * 4 + r;
            ml[(long)(z * NH + h) * N_TOK + n] = make_float2(m_i[r], lacc[r]);
        }
    }
}

// ---------------- merge KV-split partials -> attn_out bf16 (exp2 domain) ---
__global__ __launch_bounds__(256) void k_attn_merge(
    const float* __restrict__ opart, const float2* __restrict__ ml,
    bf16* __restrict__ attn_out)
{
    int n = blockIdx.x, tid = threadIdx.x;
    __shared__ float2 sml[4][NH];
    if (tid < 64) {
        int zz = tid >> 4, hh = tid & 15;
        sml[zz][hh] = ml[(long)(zz * NH + hh) * N_TOK + n];
    }
    __syncthreads();
    #pragma unroll
    for (int i = 0; i < 4; i++) {
        int c = tid + i * 256;
        int h = c >> 6;
        float M = fmaxf(fmaxf(sml[0][h].x, sml[1][h].x),
                        fmaxf(sml[2][h].x, sml[3][h].x));
        float num = 0.f, den = 0.f;
        #pragma unroll
        for (int zz = 0; zz < 4; zz++) {
            float w = exp2f(sml[zz][h].x - M);
            num += w * opart[((long)zz * N_TOK + n) * DM + c];
            den += w * sml[zz][h].y;
        }
        attn_out[(long)n * DM + c] = f2b(num / den);
    }
}

// ---------------- ODE + router + rmsnorm2 (sums dyn split partials) --------
__global__ __launch_bounds__(256) void k_ode(
    const float* __restrict__ co, const float* __restrict__ o_f,
    const float* __restrict__ velocity, const float* __restrict__ mup,
    const float* __restrict__ dyn_mu, const float* __restrict__ hidden_in,
    const float* __restrict__ mu_router_w, const int* __restrict__ token_ids,
    const float* __restrict__ ln2_w,
    float* __restrict__ out0, float* __restrict__ out_vnext,
    float* __restrict__ out_mu, bf16* __restrict__ x_bf,
    int* __restrict__ expert_id, int* __restrict__ counts)
{
    int n = blockIdx.x, tid = threadIdx.x;
    __shared__ float mu_s[DM];
    __shared__ float red2[32][8];

    #pragma unroll
    for (int i = 0; i < 4; i++) {
        int c = tid + i * 256;
        mu_s[c] = mup[(long)n * DM + c] + mup[(long)N_TOK * DM + (long)n * DM + c]
                + dyn_mu[c];
    }
    __syncthreads();

    {
        int e = tid & 7, kc = tid >> 3;
        float a = 0.f;
        #pragma unroll
        for (int kk = 0; kk < 32; kk++) {
            int k = kc * 32 + kk;
            a += mu_s[k] * mu_router_w[k * NE + e];
        }
        red2[kc][e] = a;
    }
    __syncthreads();
    if (tid == 0) {
        int bid = token_ids[n] & (NE - 1);
        float best = -1e30f; int bi = 0;
        for (int e = 0; e < NE; e++) {
            float lg = (e == bid ? 10.f : 0.f);
            for (int j = 0; j < 32; j++) lg += red2[j][e];
            if (lg > best) { best = lg; bi = e; }
        }
        expert_id[n] = bi;
        atomicAdd(&counts[bi], 1);
    }

    float ssq = 0.f;
    float h1v[4];
    #pragma unroll
    for (int i = 0; i < 4; i++) {
        int c = tid + i * 256;
        float coa = co[(long)n * 3072 + c];
        float cob = co[(long)n * 3072 + DM + c];
        float cog = co[(long)n * 3072 + 2 * DM + c];
        float alpha = 1.f / (1.f + __expf(-coa));
        float sp = (cob > 20.f) ? cob : log1pf(__expf(cob));
        float beta = fminf(sp, 2.0f);
        float gate = 1.f / (1.f + __expf(-cog));
        float ov = o_f[(long)n * DM + c];
        float vv = velocity[(long)n * DM + c];
        float err = ov - mu_s[c];
        float vn = fminf(fmaxf(alpha * vv - beta * err, -10.f), 10.f);
        float hn = ov + 0.1f * gate * vn;
        float h1 = hidden_in[(long)n * DM + c] + hn;
        h1v[i] = h1;
        ssq += h1 * h1;
        out_vnext[(long)n * DM + c] = vn;
        out_mu[(long)n * DM + c] = mu_s[c];
        out0[(long)n * DM + c] = h1;     // pre-MoE residual; k_red_down adds y
    }
    float tot = blockReduceSum256(ssq);
    float rstd = rsqrtf(tot / (float)DM + 1e-6f);
    #pragma unroll
    for (int i = 0; i < 4; i++) {
        int c = tid + i * 256;
        x_bf[(long)n * DM + c] = f2b(h1v[i] * rstd * ln2_w[c]);
    }
}

// ---------------- MoE scatter + gather, fused (offsets from counts) --------
__global__ __launch_bounds__(256) void k_scatter_gather(
    const int* __restrict__ expert_id, const int* __restrict__ counts,
    int* __restrict__ fill, int* __restrict__ perm,
    const bf16* __restrict__ x, bf16* __restrict__ xg)
{
    int n = blockIdx.x * 4 + (threadIdx.x >> 6);
    int lane = threadIdx.x & 63;
    int e = expert_id[n];
    int p = 0;
    if (lane == 0) {
        int off = 0;
        #pragma unroll
        for (int i = 0; i < NE; i++) off += (i < e) ? counts[i] : 0;
        p = off + atomicAdd(&fill[e], 1);
        perm[p] = n;
    }
    p = __shfl(p, 0, 64);
    const int4* s = (const int4*)(x + (long)n * DM);
    int4* d = (int4*)(xg + (long)p * DM);
    d[lane] = s[lane];
    d[lane + 64] = s[lane + 64];
}

__global__ __launch_bounds__(256) void k_silumul(const bf16* __restrict__ gu,
                                                 bf16* __restrict__ mid) {
    long i = ((long)blockIdx.x * 256 + threadIdx.x) * 8;   // over 2048*2048
    long r = i >> 11, c = i & 2047;
    short8 g8 = *(const short8*)(gu + r * 4096 + c);
    short8 u8 = *(const short8*)(gu + r * 4096 + 2048 + c);
    short8 o;
    #pragma unroll
    for (int j = 0; j < 8; j++) {
        short gs = g8[j], us = u8[j];
        float g = b2f(*(bf16*)&gs);
        float u = b2f(*(bf16*)&us);
        o[j] = f2s(g / (1.f + __expf(-g)) * u);
    }
    *(short8*)(mid + i) = o;
}

// ---------------- launcher ----------------
extern "C" void kernel_launch(void* const* d_in, const int* in_sizes, int n_in,
                              void* d_out, int out_size, void* d_ws, size_t ws_size,
                              hipStream_t stream) {
    (void)in_sizes; (void)n_in; (void)out_size; (void)ws_size;
    const float* hidden     = (const float*)d_in[0];
    const int*   positions  = (const int*)d_in[1];
    const float* velocity   = (const float*)d_in[2];
    const int*   token_ids  = (const int*)d_in[3];
    const float* mu_prev    = (const float*)d_in[4];
    const float* ln1_w      = (const float*)d_in[5];
    const float* ln2_w      = (const float*)d_in[6];
    const float* wq         = (const float*)d_in[7];
    const float* wk         = (const float*)d_in[8];
    const float* wv         = (const float*)d_in[9];
    const float* wo         = (const float*)d_in[10];
    const float* w_mu_q     = (const float*)d_in[11];
    const float* w_mu_k     = (const float*)d_in[12];
    const float* w_mu_v     = (const float*)d_in[13];
    const float* qnorm_w    = (const float*)d_in[14];
    const float* knorm_w    = (const float*)d_in[15];
    const float* dyn_mu     = (const float*)d_in[16];
    const float* dyn_proj   = (const float*)d_in[17];
    const float* ctrl_in_w  = (const float*)d_in[18];
    const float* ctrl_in_b  = (const float*)d_in[19];
    const float* ctrl_out_w = (const float*)d_in[20];
    const float* ctrl_out_b = (const float*)d_in[21];
    const float* mu_router  = (const float*)d_in[22];
    const float* w_gate     = (const float*)d_in[23];
    const float* w_up       = (const float*)d_in[24];
    const float* w_down     = (const float*)d_in[25];

    float* out0 = (float*)d_out;
    float* out1 = out0 + (long)N_TOK * DM;
    float* out2 = out1 + (long)N_TOK * DM;

    char* p = (char*)d_ws;
    auto alloc = [&](size_t bytes) -> void* {
        void* r = (void*)p;
        p += (bytes + 255) & ~(size_t)255;
        return r;
    };
    bf16* WqkvT   = (bf16*)alloc((long)1536 * 2048 * 2);
    bf16* woT     = (bf16*)alloc((long)1024 * 1024 * 2);
    bf16* dynT    = (bf16*)alloc((long)1024 * 1024 * 2);
    bf16* ctrlinT = (bf16*)alloc((long)64 * 2048 * 2);
    bf16* ctrloutT= (bf16*)alloc((long)3072 * 64 * 2);
    bf16* gupT    = (bf16*)alloc((long)NE * 4096 * 1024 * 2);
    bf16* downT   = (bf16*)alloc((long)NE * 1024 * 2048 * 2);
    bf16*  catA   = (bf16*)alloc((long)N_TOK * 2048 * 2);  // [h|mu_prev]; attn_bf alias
    bf16*  ctrlA  = (bf16*)alloc((long)N_TOK * 2048 * 2);  // [o_bf|vel_bf]
    float* xbuf   = (float*)alloc((long)N_TOK * 1536 * 4); // x_bf/xg_bf/ctrl-part
    bf16*  q_bf   = (bf16*)alloc((long)N_TOK * NH * DH * 2);
    bf16*  k_bf   = (bf16*)alloc((long)N_TOK * NKV * DH * 2);
    bf16*  v_bf   = (bf16*)alloc((long)N_TOK * NKV * DH * 2);
    bf16*  vt_bf  = (bf16*)alloc((long)NKV * DH * N_TOK * 2);
    float* o_f    = (float*)alloc((long)N_TOK * DM * 4);   // mid_bf alias
    float* coGu   = (float*)alloc((long)N_TOK * 3072 * 4); // ml / co / gu_bf
    float* splitb = (float*)alloc((long)4 * N_TOK * DM * 4); // split-K partials / opart
    bf16*  ctrlbf = (bf16*)alloc((long)N_TOK * CH * 2);
    int*   expert_id = (int*)alloc(N_TOK * 4);
    int*   perm      = (int*)alloc(N_TOK * 4);
    int*   counts    = (int*)alloc(64 * 4);
    int*   fill      = (int*)alloc(64 * 4);

    bf16*  attn_bf = catA;
    bf16*  x_bf    = (bf16*)xbuf;
    bf16*  xg_bf   = (bf16*)xbuf + (long)N_TOK * DM;
    float* cpart   = (float*)((bf16*)xbuf + (long)2 * N_TOK * DM);  // 8*2048*64 fp32
    float* opart   = splitb;                                // 4*2048*1024 fp32 (32 MB)
    float2* ml     = (float2*)coGu;                         // 1 MB; dead after merge
    float* co_f    = coGu;
    bf16*  gu_bf   = (bf16*)coGu;
    bf16*  mid_bf  = (bf16*)o_f;

    dim3 blk(256);

    // ---- all weight transposes (TK=256 main + TK=64 for ctrl_out) ----
    // tiles: 64 n-cols x TK k-rows; nt-major so concurrent blocks share rows
    TTab tt; int st = 0;
    auto ent = [&](int i, const float* s, bf16* d, long ss, long ds,
                   int sN, int ldk, int tN, int tK, int nE) {
        tt.t[i].src = s; tt.t[i].dst = d;
        tt.t[i].sstride = ss; tt.t[i].dstride = ds;
        tt.t[i].sN = sN; tt.t[i].ldk = ldk;
        tt.t[i].tN = tN; tt.t[i].tilesPer = tN * tK;
        tt.t[i].start = st;
        st += tN * tK * nE;
    };
    ent(0,  wq,         WqkvT,                          0, 0, 1024, 2048, 16, 4, 1);
    ent(1,  wk,         WqkvT + (long)1024 * 2048,      0, 0, 256,  2048,  4, 4, 1);
    ent(2,  wv,         WqkvT + (long)1280 * 2048,      0, 0, 256,  2048,  4, 4, 1);
    ent(3,  w_mu_q,     WqkvT + 1024,                   0, 0, 1024, 2048, 16, 4, 1);
    ent(4,  w_mu_k,     WqkvT + (long)1024 * 2048 + 1024, 0, 0, 256, 2048, 4, 4, 1);
    ent(5,  w_mu_v,     WqkvT + (long)1280 * 2048 + 1024, 0, 0, 256, 2048, 4, 4, 1);
    ent(6,  wo,         woT,                            0, 0, 1024, 1024, 16, 4, 1);
    ent(7,  dyn_proj,   dynT,                           0, 0, 1024, 1024, 16, 4, 1);
    ent(8,  ctrl_in_w,  ctrlinT,                        0, 0, 64,   2048,  1, 8, 1);
    ent(9,  w_gate,     gupT,                  (long)1024 * 2048, (long)4096 * 1024, 2048, 1024, 32, 4, 8);
    ent(10, w_up,       gupT + (long)2048 * 1024, (long)1024 * 2048, (long)4096 * 1024, 2048, 1024, 32, 4, 8);
    ent(11, w_down,     downT,                 (long)2048 * 1024, (long)1024 * 2048, 1024, 2048, 16, 8, 8);
    int stMain = st;
    ent(12, ctrl_out_w, ctrloutT,                       0, 0, 3072, 64,   48, 1, 1);
    k_transpose_all<256><<<stMain, blk, 0, stream>>>(tt, 0, counts, fill);
    k_transpose_all<64><<<st - stMain, blk, 0, stream>>>(tt, stMain, counts, fill);

    // ---- activation prep (rmsnorm + 2 casts fused) ----
    k_prep<<<N_TOK, blk, 0, stream>>>(hidden, ln1_w, mu_prev, velocity, catA, ctrlA);

    // ---- QKV: [h|mu] @ [Wqkv; Wmu]  split-K2 -> partials in splitb ----
    k_gemm<<<dim3(12,16,2), blk, 0, stream>>>(catA, 2048, WqkvT, 2048, 0,
        splitb, 1536, nullptr, nullptr, 0, 2048, 0, 2, (long)N_TOK * 1536,
        nullptr, nullptr, nullptr);

    k_qkv_post<<<N_TOK, blk, 0, stream>>>(splitb, positions, qnorm_w, knorm_w, q_bf, k_bf, v_bf);
    k_vt<<<dim3(32,1,NKV), blk, 0, stream>>>(v_bf, vt_bf);
    k_attn<<<dim3(32,16,4), blk, 0, stream>>>(q_bf, k_bf, vt_bf, opart, ml);
    k_attn_merge<<<N_TOK, blk, 0, stream>>>(opart, ml, attn_bf);

    // ---- o = attn @ wo  split-K2; reduce -> o_f fp32 + ctrlA bf16 ----
    k_gemm<<<dim3(8,16,2), blk, 0, stream>>>(attn_bf, 1024, woT, 1024, 0,
        splitb, 1024, nullptr, nullptr, 0, 1024, 0, 2, (long)N_TOK * DM,
        nullptr, nullptr, nullptr);
    k_red_wo<<<N_TOK, blk, 0, stream>>>(splitb, o_f, ctrlA);

    // ---- mu = dyn_mu + o @ dyn_proj  split-K2 (summed inside k_ode) ----
    k_gemm<<<dim3(8,16,2), blk, 0, stream>>>(ctrlA, 2048, dynT, 1024, 0,
        splitb, 1024, nullptr, nullptr, 0, 1024, 0, 2, (long)N_TOK * DM,
        nullptr, nullptr, nullptr);

    // ---- ctrl chain ----
    k_ctrl_gemm<<<dim3(16,8,1), blk, 0, stream>>>(ctrlA, ctrlinT, cpart);
    k_silu_ctrl<<<(N_TOK * CH) / 1024, blk, 0, stream>>>(cpart, ctrl_in_b, ctrlbf);
    k_gemm<<<dim3(24,16,1), blk, 0, stream>>>(ctrlbf, 64, ctrloutT, 64, 0,
        co_f, 3072, ctrl_out_b, nullptr, 0, 64, GEMM_WRITE | GEMM_BIAS, 1, 0,
        nullptr, nullptr, nullptr);

    k_ode<<<N_TOK, blk, 0, stream>>>(co_f, o_f, velocity, splitb, dyn_mu, hidden,
        mu_router, token_ids, ln2_w, out0, out1, out2, x_bf, expert_id, counts);

    k_scatter_gather<<<N_TOK / 4, blk, 0, stream>>>(expert_id, counts, fill, perm,
        x_bf, xg_bf);

    // ---- MoE: [gate|up] combined (N=4096), silu*mul, down split-K4 ----
    k_gemm<<<dim3(32,16,NE), blk, 0, stream>>>(xg_bf, 1024, gupT, 1024, (long)4096*1024,
        nullptr, 0, nullptr, gu_bf, 4096, 1024, GEMM_WRITEB, 1, 0,
        counts, nullptr, nullptr);
    k_silumul<<<(N_TOK * FF) / (256 * 8), blk, 0, stream>>>(gu_bf, mid_bf);
    k_gemm<<<dim3(8,16,NE*4), blk, 0, stream>>>(mid_bf, 2048, downT, 2048, (long)1024*2048,
        splitb, 1024, nullptr, nullptr, 0, 2048, 0, 4, (long)N_TOK * DM,
        counts, nullptr, nullptr);
    k_red_down<<<N_TOK, blk, 0, stream>>>(splitb, perm, out0);
}

// Round 4
// 578.112 us; speedup vs baseline: 1.0975x; 1.0975x over previous
//
#include <hip/hip_runtime.h>
#include <hip/hip_bf16.h>
#include <math.h>

typedef __hip_bfloat16 bf16;
typedef __attribute__((ext_vector_type(8))) short short8;
typedef __attribute__((ext_vector_type(4))) short short4v;
typedef __attribute__((ext_vector_type(4))) float floatx4;

#define N_TOK 2048
#define DM    1024
#define NH    16
#define NKV   4
#define DH    64
#define NE    8
#define FF    2048
#define CH    64
#define QSCL  0.18033688011112042f   /* (1/sqrt(64)) * log2(e) */

__device__ __forceinline__ float b2f(bf16 x) { return __bfloat162float(x); }
__device__ __forceinline__ bf16  f2b(float x) { return __float2bfloat16(x); }
__device__ __forceinline__ short f2s(float x) { bf16 t = __float2bfloat16(x); return *(short*)&t; }

#define MFMA16(a, b, c) __builtin_amdgcn_mfma_f32_16x16x32_bf16(a, b, c, 0, 0, 0)

// async global->LDS, 16B per lane; LDS dest = wave-uniform base + lane*16
#define GLL16(g, l) __builtin_amdgcn_global_load_lds( \
    (const __attribute__((address_space(1))) void*)(g), \
    (__attribute__((address_space(3))) void*)(l), 16, 0, 0)

__device__ __forceinline__ float blockReduceSum256(float v) {
    __shared__ float tmp[4];
    #pragma unroll
    for (int m = 1; m < 64; m <<= 1) v += __shfl_xor(v, m, 64);
    if ((threadIdx.x & 63) == 0) tmp[threadIdx.x >> 6] = v;
    __syncthreads();
    float r = tmp[0] + tmp[1] + tmp[2] + tmp[3];
    __syncthreads();
    return r;
}

// ---------------- transpose: small weights only (MoE weights stay fp32) ----
// fp32 KxN -> bf16 NxK, 64n x TK tiles (see R3 notes). ~21 MB total now.
struct TEnt {
    const float* src; bf16* dst;
    long sstride, dstride;
    int sN, ldk, tN, tilesPer, start;
};
struct TTab { TEnt t[13]; };

template <int TK>
__global__ __launch_bounds__(256) void k_transpose_all(TTab tab, int base,
                                                       int* counts, int* fill) {
    if (base == 0 && blockIdx.x == 0 && threadIdx.x < NE) {
        counts[threadIdx.x] = 0;
        fill[threadIdx.x] = 0;
    }
    int b = blockIdx.x + base;
    int wi = 0;
    #pragma unroll
    for (int i = 1; i < 13; i++) if (b >= tab.t[i].start) wi = i;
    const TEnt& w = tab.t[wi];
    int local = b - w.start;
    int e = local / w.tilesPer; local -= e * w.tilesPer;
    int kt = local / w.tN, nt = local - kt * w.tN;
    const float* s = w.src + (long)e * w.sstride + (long)(kt * TK) * w.sN + nt * 64;
    bf16* d = w.dst + (long)e * w.dstride + (long)(nt * 64) * w.ldk + kt * TK;

    __shared__ short t16[64 * TK];
    int tid = threadIdx.x;
    int c4 = (tid & 15) * 4;

    #pragma unroll
    for (int j = 0; j < (TK / 8 + 15) / 16; j++) {
        int kk8 = 8 * ((tid >> 4) + 16 * j);
        if (kk8 < TK) {
            float4 rr[8];
            #pragma unroll
            for (int t = 0; t < 8; t++)
                rr[t] = *(const float4*)(s + (long)(kk8 + t) * w.sN + c4);
            #pragma unroll
            for (int q = 0; q < 4; q++) {
                int n = c4 + q;
                int ks = kk8 ^ ((n & 7) << 3);
                short8 o;
                #pragma unroll
                for (int t = 0; t < 8; t++) o[t] = f2s(((const float*)&rr[t])[q]);
                *(short8*)&t16[n * TK + ks] = o;
            }
        }
    }
    __syncthreads();
    const int cpr = TK / 8;   // 16B chunks per dst row
    #pragma unroll
    for (int rnd = 0; rnd < TK / 32; rnd++) {
        int id = tid + rnd * 256;
        int n = id / cpr;
        int kc = (id % cpr) * 8;
        int ks = kc ^ ((n & 7) << 3);
        short8 o = *(const short8*)&t16[n * TK + ks];
        *(short8*)(d + (long)n * w.ldk + kc) = o;
    }
}

// ---------------- fused: rmsnorm(hidden)->catA[:,0:1024], cvt mu/vel -------
__global__ __launch_bounds__(256) void k_prep(
    const float* __restrict__ hidden, const float* __restrict__ ln1_w,
    const float* __restrict__ mu_prev, const float* __restrict__ velocity,
    bf16* __restrict__ catA, bf16* __restrict__ ctrlA)
{
    int n = blockIdx.x, tid = threadIdx.x;
    float ss = 0.f, vals[4];
    #pragma unroll
    for (int i = 0; i < 4; i++) {
        int c = tid + i * 256;
        vals[i] = hidden[(long)n * DM + c];
        ss += vals[i] * vals[i];
        catA[(long)n * 2048 + 1024 + c] = f2b(mu_prev[(long)n * DM + c]);
        ctrlA[(long)n * 2048 + 1024 + c] = f2b(velocity[(long)n * DM + c]);
    }
    float tot = blockReduceSum256(ss);
    float r = rsqrtf(tot / (float)DM + 1e-6f);
    #pragma unroll
    for (int i = 0; i < 4; i++) {
        int c = tid + i * 256;
        catA[(long)n * 2048 + c] = f2b(vals[i] * r * ln1_w[c]);
    }
}

// ---------------- generic 128x128 MFMA GEMM, bf16 A (MxK) x bf16 B^T (NxK) -
#define GEMM_WRITE  1
#define GEMM_BIAS   2
#define GEMM_WRITEB 4

__global__ __launch_bounds__(256) void k_gemm(
    const bf16* __restrict__ A, int lda,
    const bf16* __restrict__ Bt, int ldb, long strideBe,
    float* __restrict__ C, int ldc,
    const float* __restrict__ bias,
    bf16* __restrict__ Cb, int ldcb,
    int K, int flags,
    int nsplit, long strideKc,
    const int* __restrict__ grp_cnt)
{
    __shared__ __align__(16) short As[128 * 32];
    __shared__ __align__(16) short Bs[128 * 32];
    int tid = threadIdx.x;
    int e = blockIdx.z, kc = 0;
    if (nsplit > 1) { e = blockIdx.z / nsplit; kc = blockIdx.z % nsplit; }
    int rowBase, rowsValid;
    const bf16* Bp = Bt;
    if (grp_cnt) {
        int r0 = 0;
        #pragma unroll
        for (int i = 0; i < NE; i++) r0 += (i < e) ? grp_cnt[i] : 0;
        int r1 = r0 + grp_cnt[e];
        int rt = blockIdx.y * 128;
        rowsValid = (r1 - r0) - rt;
        if (rowsValid <= 0) return;
        if (rowsValid > 128) rowsValid = 128;
        rowBase = r0 + rt;
        Bp = Bt + (long)e * strideBe;
    } else {
        rowBase = blockIdx.y * 128;
        rowsValid = 128;
    }
    int n0 = blockIdx.x * 128;
    int Kc = K / nsplit;
    int kbeg = kc * Kc, kend = kbeg + Kc;

    floatx4 acc[4][4];
    #pragma unroll
    for (int i = 0; i < 4; i++)
        #pragma unroll
        for (int j = 0; j < 4; j++) acc[i][j] = (floatx4){0.f, 0.f, 0.f, 0.f};

    int wave = tid >> 6, lane = tid & 63;
    int wm = (wave >> 1) * 64, wn = (wave & 1) * 64;
    int lrow = lane & 15, quad = lane >> 4;

    int c0 = wave * 2;
    int srow0 = c0 * 16 + (lane >> 2);
    int srow1 = (c0 + 1) * 16 + (lane >> 2);
    int skoff = (lane & 3) * 8;
    short* ldsA0 = As + c0 * 512;
    short* ldsA1 = As + (c0 + 1) * 512;
    short* ldsB0 = Bs + c0 * 512;
    short* ldsB1 = Bs + (c0 + 1) * 512;

    for (int k0 = kbeg; k0 < kend; k0 += 32) {
        if (srow0 < rowsValid) GLL16(A + (long)(rowBase + srow0) * lda + k0 + skoff, ldsA0);
        if (srow1 < rowsValid) GLL16(A + (long)(rowBase + srow1) * lda + k0 + skoff, ldsA1);
        GLL16(Bp + (long)(n0 + srow0) * ldb + k0 + skoff, ldsB0);
        GLL16(Bp + (long)(n0 + srow1) * ldb + k0 + skoff, ldsB1);
        __syncthreads();
        short8 af[4], bfr[4];
        #pragma unroll
        for (int mi = 0; mi < 4; mi++)
            af[mi] = *(const short8*)(&As[(wm + mi * 16 + lrow) * 32 + quad * 8]);
        #pragma unroll
        for (int ni = 0; ni < 4; ni++)
            bfr[ni] = *(const short8*)(&Bs[(wn + ni * 16 + lrow) * 32 + quad * 8]);
        #pragma unroll
        for (int mi = 0; mi < 4; mi++)
            #pragma unroll
            for (int ni = 0; ni < 4; ni++)
                acc[mi][ni] = MFMA16(af[mi], bfr[ni], acc[mi][ni]);
        __syncthreads();
    }

    #pragma unroll
    for (int mi = 0; mi < 4; mi++) {
        #pragma unroll
        for (int ni = 0; ni < 4; ni++) {
            #pragma unroll
            for (int r = 0; r < 4; r++) {
                int rl = wm + mi * 16 + quad * 4 + r;
                if (rl >= rowsValid) continue;
                int grow = rowBase + rl;
                int gcol = n0 + wn + ni * 16 + lrow;
                float v = acc[mi][ni][r];
                if (nsplit > 1) {
                    C[kc * strideKc + (long)grow * ldc + gcol] = v;
                    continue;
                }
                if (flags & GEMM_BIAS) v += bias[gcol];
                if (flags & GEMM_WRITE) C[(long)grow * ldc + gcol] = v;
                if (flags & GEMM_WRITEB) Cb[(long)grow * ldcb + gcol] = f2b(v);
            }
        }
    }
}

// ---------------- MFMA GEMM with fp32 KxN B (on-the-fly cvt, no transpose) -
// B tile (32k x 128n fp32) staged linearly via GLL16, then in-LDS transpose:
// thread reads 4 k at fixed n (stride-512B -> conflict-free), cvt, one
// ds_write_b64 into Bs2 [128n][40] (stride 80B, 16B-aligned frag reads).
__global__ __launch_bounds__(256) void k_gemm_f32b(
    const bf16* __restrict__ A, int lda,
    const float* __restrict__ Bf0, const float* __restrict__ Bf1,
    int ldbn, long strideBfe, int nbf0,
    float* __restrict__ C, int ldc,
    bf16* __restrict__ Cb, int ldcb,
    int K, int flags,
    int nsplit, long strideKc,
    const int* __restrict__ grp_cnt)
{
    __shared__ __align__(16) short As[128 * 32];
    __shared__ __align__(16) float Braw[32 * 128];
    __shared__ __align__(16) short Bs2[128 * 40];
    int tid = threadIdx.x;
    int e = blockIdx.z, kc = 0;
    if (nsplit > 1) { e = blockIdx.z / nsplit; kc = blockIdx.z % nsplit; }
    int r0 = 0;
    #pragma unroll
    for (int i = 0; i < NE; i++) r0 += (i < e) ? grp_cnt[i] : 0;
    int r1 = r0 + grp_cnt[e];
    int rt = blockIdx.y * 128;
    int rowsValid = (r1 - r0) - rt;
    if (rowsValid <= 0) return;
    if (rowsValid > 128) rowsValid = 128;
    int rowBase = r0 + rt;

    int n0 = blockIdx.x * 128;
    const float* Bsrc;
    int nb;
    if (n0 < nbf0) { Bsrc = Bf0; nb = n0; }
    else           { Bsrc = Bf1; nb = n0 - nbf0; }
    Bsrc += (long)e * strideBfe;

    int Kc = K / nsplit;
    int kbeg = kc * Kc, kend = kbeg + Kc;

    floatx4 acc[4][4];
    #pragma unroll
    for (int i = 0; i < 4; i++)
        #pragma unroll
        for (int j = 0; j < 4; j++) acc[i][j] = (floatx4){0.f, 0.f, 0.f, 0.f};

    int wave = tid >> 6, lane = tid & 63;
    int wm = (wave >> 1) * 64, wn = (wave & 1) * 64;
    int lrow = lane & 15, quad = lane >> 4;

    // A staging coords (same as k_gemm)
    int c0 = wave * 2;
    int srow0 = c0 * 16 + (lane >> 2);
    int srow1 = (c0 + 1) * 16 + (lane >> 2);
    int skoff = (lane & 3) * 8;
    short* ldsA0 = As + c0 * 512;
    short* ldsA1 = As + (c0 + 1) * 512;

    // B staging coords: GLL16 r covers floats [(r*4+wave)*256 + lane*4 ..+3]
    //   -> k = (r*8 + wave*2 + (lane>>5)), nc = (lane&31)*4
    int kB = wave * 2 + (lane >> 5);
    int ncB = (lane & 31) * 4;

    for (int k0 = kbeg; k0 < kend; k0 += 32) {
        if (srow0 < rowsValid) GLL16(A + (long)(rowBase + srow0) * lda + k0 + skoff, ldsA0);
        if (srow1 < rowsValid) GLL16(A + (long)(rowBase + srow1) * lda + k0 + skoff, ldsA1);
        #pragma unroll
        for (int r = 0; r < 4; r++)
            GLL16(Bsrc + (long)(k0 + r * 8 + kB) * ldbn + nb + ncB,
                  Braw + r * 1024 + wave * 256);
        __syncthreads();

        // in-LDS transpose + cvt: Braw [32k][128n] f32 -> Bs2 [128n][40] bf16
        #pragma unroll
        for (int r2 = 0; r2 < 4; r2++) {
            int id = r2 * 256 + tid;
            int n = id & 127, kb = id >> 7;
            float f0 = Braw[(kb * 4 + 0) * 128 + n];
            float f1 = Braw[(kb * 4 + 1) * 128 + n];
            float f2 = Braw[(kb * 4 + 2) * 128 + n];
            float f3 = Braw[(kb * 4 + 3) * 128 + n];
            short4v o;
            o[0] = f2s(f0); o[1] = f2s(f1); o[2] = f2s(f2); o[3] = f2s(f3);
            *(short4v*)&Bs2[n * 40 + kb * 4] = o;
        }
        short8 af[4];
        #pragma unroll
        for (int mi = 0; mi < 4; mi++)
            af[mi] = *(const short8*)(&As[(wm + mi * 16 + lrow) * 32 + quad * 8]);
        __syncthreads();

        short8 bfr[4];
        #pragma unroll
        for (int ni = 0; ni < 4; ni++)
            bfr[ni] = *(const short8*)(&Bs2[(wn + ni * 16 + lrow) * 40 + quad * 8]);
        #pragma unroll
        for (int mi = 0; mi < 4; mi++)
            #pragma unroll
            for (int ni = 0; ni < 4; ni++)
                acc[mi][ni] = MFMA16(af[mi], bfr[ni], acc[mi][ni]);
    }
    __syncthreads();

    #pragma unroll
    for (int mi = 0; mi < 4; mi++) {
        #pragma unroll
        for (int ni = 0; ni < 4; ni++) {
            #pragma unroll
            for (int r = 0; r < 4; r++) {
                int rl = wm + mi * 16 + quad * 4 + r;
                if (rl >= rowsValid) continue;
                int grow = rowBase + rl;
                int gcol = n0 + wn + ni * 16 + lrow;
                float v = acc[mi][ni][r];
                if (nsplit > 1) {
                    C[kc * strideKc + (long)grow * ldc + gcol] = v;
                } else if (flags & GEMM_WRITEB) {
                    Cb[(long)grow * ldcb + gcol] = f2b(v);
                }
            }
        }
    }
}

// ---------------- split-K reduce: wo (o_f fp32 + ctrlA bf16) ---------------
__global__ __launch_bounds__(256) void k_red_wo(const float* __restrict__ p,
                                                float* __restrict__ o_f,
                                                bf16* __restrict__ ctrlA) {
    int n = blockIdx.x, tid = threadIdx.x;
    #pragma unroll
    for (int i = 0; i < 4; i++) {
        int c = tid + i * 256;
        float v = p[(long)n * DM + c] + p[(long)N_TOK * DM + (long)n * DM + c];
        o_f[(long)n * DM + c] = v;
        ctrlA[(long)n * 2048 + c] = f2b(v);
    }
}

// ---------------- split-K reduce: down (4 partials, perm scatter, +=) ------
__global__ __launch_bounds__(256) void k_red_down(const float* __restrict__ p,
                                                  const int* __restrict__ perm,
                                                  float* __restrict__ out0) {
    int r = blockIdx.x, tid = threadIdx.x;
    int tok = perm[r];
    #pragma unroll
    for (int i = 0; i < 4; i++) {
        int c = tid + i * 256;
        long idx = (long)r * DM + c;
        float v = p[idx] + p[(long)N_TOK * DM + idx] +
                  p[(long)2 * N_TOK * DM + idx] + p[(long)3 * N_TOK * DM + idx];
        out0[(long)tok * DM + c] += v;
    }
}

// ---------------- ctrl_in GEMM: part[kc] = [o|vel] @ W_in (K-chunked) ------
__global__ __launch_bounds__(256) void k_ctrl_gemm(
    const bf16* __restrict__ A,      // ctrlA 2048 x 2048
    const bf16* __restrict__ Bt,     // ctrl_inT 64 x 2048
    float* __restrict__ part)        // [8][2048][64]
{
    __shared__ __align__(16) short As[128 * 32];
    __shared__ __align__(16) short Bs[64 * 32];
    int tid = threadIdx.x;
    int rowBase = blockIdx.x * 128;
    int kbeg = blockIdx.y * 256;
    int wave = tid >> 6, lane = tid & 63;
    int wm = wave * 32, lrow = lane & 15, quad = lane >> 4;
    int srow = lane >> 2, skoff = (lane & 3) * 8;

    floatx4 acc[2][4];
    #pragma unroll
    for (int i = 0; i < 2; i++)
        #pragma unroll
        for (int j = 0; j < 4; j++) acc[i][j] = (floatx4){0.f, 0.f, 0.f, 0.f};

    short* ldsA0 = As + (wave * 2) * 512;
    short* ldsA1 = As + (wave * 2 + 1) * 512;
    short* ldsB  = Bs + wave * 512;

    for (int k0 = kbeg; k0 < kbeg + 256; k0 += 32) {
        GLL16(A + (long)(rowBase + wave * 32 + srow) * 2048 + k0 + skoff, ldsA0);
        GLL16(A + (long)(rowBase + wave * 32 + 16 + srow) * 2048 + k0 + skoff, ldsA1);
        GLL16(Bt + (long)(wave * 16 + srow) * 2048 + k0 + skoff, ldsB);
        __syncthreads();
        short8 af[2], bfr[4];
        af[0] = *(const short8*)(&As[(wm + lrow) * 32 + quad * 8]);
        af[1] = *(const short8*)(&As[(wm + 16 + lrow) * 32 + quad * 8]);
        #pragma unroll
        for (int ni = 0; ni < 4; ni++)
            bfr[ni] = *(const short8*)(&Bs[(ni * 16 + lrow) * 32 + quad * 8]);
        #pragma unroll
        for (int mi = 0; mi < 2; mi++)
            #pragma unroll
            for (int ni = 0; ni < 4; ni++)
                acc[mi][ni] = MFMA16(af[mi], bfr[ni], acc[mi][ni]);
        __syncthreads();
    }
    #pragma unroll
    for (int mi = 0; mi < 2; mi++)
        #pragma unroll
        for (int ni = 0; ni < 4; ni++)
            #pragma unroll
            for (int r = 0; r < 4; r++) {
                int grow = rowBase + wm + mi * 16 + quad * 4 + r;
                part[((long)blockIdx.y * N_TOK + grow) * 64 + ni * 16 + lrow] = acc[mi][ni][r];
            }
}

__global__ __launch_bounds__(256) void k_silu_ctrl(const float* __restrict__ part,
                                                   const float* __restrict__ b,
                                                   bf16* __restrict__ out) {
    int i4 = (blockIdx.x * 256 + threadIdx.x) * 4;   // over 2048*64
    float4 a = *(const float4*)(b + (i4 & 63));
    #pragma unroll
    for (int kc = 0; kc < 8; kc++) {
        float4 p = *(const float4*)(part + (long)kc * (N_TOK * 64) + i4);
        a.x += p.x; a.y += p.y; a.z += p.z; a.w += p.w;
    }
    short4v o;
    o[0] = f2s(a.x / (1.f + __expf(-a.x)));
    o[1] = f2s(a.y / (1.f + __expf(-a.y)));
    o[2] = f2s(a.z / (1.f + __expf(-a.z)));
    o[3] = f2s(a.w / (1.f + __expf(-a.w)));
    *(short4v*)(out + i4) = o;
}

// ---------------- qk norm + rope + split (sums 2 K-split partials) ---------
// NOTE: Q is pre-scaled by QSCL (softmax runs in exp2 domain downstream).
__global__ __launch_bounds__(256) void k_qkv_post(
    const float* __restrict__ qkvp, const int* __restrict__ positions,
    const float* __restrict__ qnw, const float* __restrict__ knw,
    bf16* __restrict__ q, bf16* __restrict__ k, bf16* __restrict__ v)
{
    int n = blockIdx.x;
    int wave = threadIdx.x >> 6, lane = threadIdx.x & 63;
    float pos = (float)positions[n];
    int i = lane & 31;
    float invf = exp2f(-(float)(2 * i) * (13.287712379549449f / 64.f));
    float ang = pos * invf;
    float c = cosf(ang), s = sinf(ang);

    #pragma unroll
    for (int si = 0; si < 6; si++) {
        int slot = wave + si * 4;  // 0..23
        long base = (long)n * 1536 +
                    (slot < 16 ? slot * 64
                               : (slot < 20 ? 1024 + (slot - 16) * 64
                                            : 1280 + (slot - 20) * 64));
        float val = qkvp[base + lane] + qkvp[(long)N_TOK * 1536 + base + lane];
        if (slot < 20) {
            float ss = val * val;
            #pragma unroll
            for (int m = 1; m < 64; m <<= 1) ss += __shfl_xor(ss, m, 64);
            float r = rsqrtf(ss / 64.f + 1e-6f);
            float wn = (slot < 16 ? qnw[lane] : knw[lane]);
            float xn = val * r * wn;
            float partner = __shfl_xor(xn, 32, 64);
            float out = (lane < 32) ? (xn * c - partner * s) : (xn * c + partner * s);
            if (slot < 16) q[((long)n * NH + slot) * 64 + lane] = f2b(out * QSCL);
            else           k[((long)n * NKV + (slot - 16)) * 64 + lane] = f2b(out);
        } else {
            v[((long)n * NKV + (slot - 20)) * 64 + lane] = f2b(val);
        }
    }
}

// ---------------- V transpose: v[n][kv][d] -> vt[kv*64+d][n] ---------------
__global__ __launch_bounds__(256) void k_vt(const bf16* __restrict__ v,
                                            bf16* __restrict__ vt) {
    __shared__ short tile[64][65];
    int kv = blockIdx.z, n0 = blockIdx.x * 64;
    int tid = threadIdx.x;
    int c = tid & 63, r4 = tid >> 6;
    const short* vs = (const short*)v;
    #pragma unroll
    for (int i = 0; i < 16; i++) {
        int r = i * 4 + r4;
        tile[r][c] = vs[(long)(n0 + r) * 256 + kv * 64 + c];
    }
    __syncthreads();
    #pragma unroll
    for (int i = 0; i < 16; i++) {
        int d = i * 4 + r4;
        ((short*)vt)[(long)(kv * 64 + d) * 2048 + n0 + c] = tile[c][d];
    }
}

// ---------------- flash attention, KV-split 4 (partials) -------------------
__device__ __forceinline__ int lds_idx(int row, int col_sh) {
    int byteoff = col_sh * 2;
    byteoff ^= (row & 7) << 4;            // swizzle 16B blocks within row
    return row * 64 + (byteoff >> 1);
}

__global__ __launch_bounds__(256) void k_attn(
    const bf16* __restrict__ q, const bf16* __restrict__ k,
    const bf16* __restrict__ vt,
    float* __restrict__ opart, float2* __restrict__ ml)
{
    const int h = blockIdx.y;
    const int qbase = blockIdx.x * 64;
    const int z = blockIdx.z;
    const int kvh = h >> 2;
    __shared__ __align__(16) short Ks[64 * 64];
    __shared__ __align__(16) short Vt[64 * 64];
    __shared__ __align__(16) short Ps[64 * 64];
    int tid = threadIdx.x, wave = tid >> 6, lane = tid & 63;
    int lrow = lane & 15, quad = lane >> 4;

    const bf16* qp = q + ((long)(qbase + wave * 16 + lrow) * NH + h) * 64;
    short8 aq0 = *(const short8*)(qp + quad * 8);
    short8 aq1 = *(const short8*)(qp + 32 + quad * 8);

    short8 bones;
    #pragma unroll
    for (int j = 0; j < 8; j++) bones[j] = (short)0x3F80;  // bf16 1.0

    const int lin0 = tid, lin1 = tid + 256;
    const int sr0 = lin0 >> 3, sc0 = (lin0 & 7) * 8;
    const int sr1 = lin1 >> 3, sc1 = (lin1 & 7) * 8;
    const int wi0 = lds_idx(sr0, sc0), wi1 = lds_idx(sr1, sc1);

    const int kt0 = z * (N_TOK / 4);
    const bf16* kg0 = k + ((long)(kt0 + sr0) * NKV + kvh) * 64 + sc0;
    const bf16* kg1 = k + ((long)(kt0 + sr1) * NKV + kvh) * 64 + sc1;
    const bf16* vg0 = vt + (long)(kvh * 64 + sr0) * 2048 + kt0 + sc0;
    const bf16* vg1 = vt + (long)(kvh * 64 + sr1) * 2048 + kt0 + sc1;

    *(short8*)&Ks[wi0] = *(const short8*)kg0;
    *(short8*)&Ks[wi1] = *(const short8*)kg1;
    *(short8*)&Vt[wi0] = *(const short8*)vg0;
    *(short8*)&Vt[wi1] = *(const short8*)vg1;

    float m_i[4];
    floatx4 lacc = (floatx4){0.f, 0.f, 0.f, 0.f};
    floatx4 oacc[4];
    #pragma unroll
    for (int r = 0; r < 4; r++) m_i[r] = -1e30f;
    #pragma unroll
    for (int di = 0; di < 4; di++) oacc[di] = (floatx4){0.f, 0.f, 0.f, 0.f};
    __syncthreads();

    const int NT = (N_TOK / 4) / 64;   // 8 tiles per block
    for (int t = 0; t < NT; t++) {
        bool pf = (t + 1 < NT);
        short8 nk0, nk1, nv0, nv1;
        if (pf) {
            long ko = (long)(t + 1) * (64 * NKV * 64);
            int  vo = (t + 1) * 64;
            nk0 = *(const short8*)(kg0 + ko);
            nk1 = *(const short8*)(kg1 + ko);
            nv0 = *(const short8*)(vg0 + vo);
            nv1 = *(const short8*)(vg1 + vo);
        }

        floatx4 sv[4];
        __builtin_amdgcn_s_setprio(1);
        #pragma unroll
        for (int kn = 0; kn < 4; kn++) {
            short8 b0 = *(const short8*)&Ks[lds_idx(kn * 16 + lrow, quad * 8)];
            short8 b1 = *(const short8*)&Ks[lds_idx(kn * 16 + lrow, 32 + quad * 8)];
            floatx4 tt = (floatx4){0.f, 0.f, 0.f, 0.f};
            tt = MFMA16(aq0, b0, tt);
            tt = MFMA16(aq1, b1, tt);
            sv[kn] = tt;
        }
        __builtin_amdgcn_s_setprio(0);

        float mx[4];
        #pragma unroll
        for (int r = 0; r < 4; r++) {
            float m0 = fmaxf(fmaxf(sv[0][r], sv[1][r]), fmaxf(sv[2][r], sv[3][r]));
            #pragma unroll
            for (int msk = 1; msk < 16; msk <<= 1) m0 = fmaxf(m0, __shfl_xor(m0, msk, 64));
            mx[r] = m0;
        }
        int ok = (mx[0] <= m_i[0] + 8.f) & (mx[1] <= m_i[1] + 8.f) &
                 (mx[2] <= m_i[2] + 8.f) & (mx[3] <= m_i[3] + 8.f);
        if (!__all(ok)) {
            #pragma unroll
            for (int r = 0; r < 4; r++) {
                float mn = fmaxf(m_i[r], mx[r]);
                float al = exp2f(m_i[r] - mn);
                m_i[r] = mn;
                lacc[r] *= al;
                #pragma unroll
                for (int di = 0; di < 4; di++) oacc[di][r] *= al;
            }
        }
        #pragma unroll
        for (int kn = 0; kn < 4; kn++)
            #pragma unroll
            for (int r = 0; r < 4; r++)
                sv[kn][r] = exp2f(sv[kn][r] - m_i[r]);

        #pragma unroll
        for (int kn = 0; kn < 4; kn++)
            #pragma unroll
            for (int r = 0; r < 4; r++)
                Ps[lds_idx(wave * 16 + quad * 4 + r, kn * 16 + lrow)] = f2s(sv[kn][r]);
        __syncthreads();

        short8 ap0 = *(const short8*)&Ps[lds_idx(wave * 16 + lrow, quad * 8)];
        short8 ap1 = *(const short8*)&Ps[lds_idx(wave * 16 + lrow, 32 + quad * 8)];
        __builtin_amdgcn_s_setprio(1);
        lacc = MFMA16(ap0, bones, lacc);
        lacc = MFMA16(ap1, bones, lacc);
        #pragma unroll
        for (int di = 0; di < 4; di++) {
            short8 bv0 = *(const short8*)&Vt[lds_idx(di * 16 + lrow, quad * 8)];
            short8 bv1 = *(const short8*)&Vt[lds_idx(di * 16 + lrow, 32 + quad * 8)];
            oacc[di] = MFMA16(ap0, bv0, oacc[di]);
            oacc[di] = MFMA16(ap1, bv1, oacc[di]);
        }
        __builtin_amdgcn_s_setprio(0);
        __syncthreads();

        if (pf) {
            *(short8*)&Ks[wi0] = nk0;
            *(short8*)&Ks[wi1] = nk1;
            *(short8*)&Vt[wi0] = nv0;
            *(short8*)&Vt[wi1] = nv1;
            __syncthreads();
        }
    }

    #pragma unroll
    for (int di = 0; di < 4; di++)
        #pragma unroll
        for (int r = 0; r < 4; r++) {
            int n = qbase + wave * 16 + quad * 4 + r;
            opart[((long)z * N_TOK + n) * DM + h * 64 + di * 16 + lrow] = oacc[di][r];
        }
    if (lrow == 0) {
        #pragma unroll
        for (int r = 0; r < 4; r++) {
            int n = qbase + wave * 16 + quad * 4 + r;
            ml[(long)(z * NH + h) * N_TOK + n] = make_float2(m_i[r], lacc[r]);
        }
    }
}

// ---------------- merge KV-split partials -> attn_out bf16 (exp2 domain) ---
__global__ __launch_bounds__(256) void k_attn_merge(
    const float* __restrict__ opart, const float2* __restrict__ ml,
    bf16* __restrict__ attn_out)
{
    int n = blockIdx.x, tid = threadIdx.x;
    __shared__ float2 sml[4][NH];
    if (tid < 64) {
        int zz = tid >> 4, hh = tid & 15;
        sml[zz][hh] = ml[(long)(zz * NH + hh) * N_TOK + n];
    }
    __syncthreads();
    #pragma unroll
    for (int i = 0; i < 4; i++) {
        int c = tid + i * 256;
        int h = c >> 6;
        float M = fmaxf(fmaxf(sml[0][h].x, sml[1][h].x),
                        fmaxf(sml[2][h].x, sml[3][h].x));
        float num = 0.f, den = 0.f;
        #pragma unroll
        for (int zz = 0; zz < 4; zz++) {
            float w = exp2f(sml[zz][h].x - M);
            num += w * opart[((long)zz * N_TOK + n) * DM + c];
            den += w * sml[zz][h].y;
        }
        attn_out[(long)n * DM + c] = f2b(num / den);
    }
}

// ---------------- ODE + router + rmsnorm2 (sums dyn split partials) --------
__global__ __launch_bounds__(256) void k_ode(
    const float* __restrict__ co, const float* __restrict__ o_f,
    const float* __restrict__ velocity, const float* __restrict__ mup,
    const float* __restrict__ dyn_mu, const float* __restrict__ hidden_in,
    const float* __restrict__ mu_router_w, const int* __restrict__ token_ids,
    const float* __restrict__ ln2_w,
    float* __restrict__ out0, float* __restrict__ out_vnext,
    float* __restrict__ out_mu, bf16* __restrict__ x_bf,
    int* __restrict__ expert_id, int* __restrict__ counts)
{
    int n = blockIdx.x, tid = threadIdx.x;
    __shared__ float mu_s[DM];
    __shared__ float red2[32][8];

    #pragma unroll
    for (int i = 0; i < 4; i++) {
        int c = tid + i * 256;
        mu_s[c] = mup[(long)n * DM + c] + mup[(long)N_TOK * DM + (long)n * DM + c]
                + dyn_mu[c];
    }
    __syncthreads();

    {
        int e = tid & 7, kc = tid >> 3;
        float a = 0.f;
        #pragma unroll
        for (int kk = 0; kk < 32; kk++) {
            int k = kc * 32 + kk;
            a += mu_s[k] * mu_router_w[k * NE + e];
        }
        red2[kc][e] = a;
    }
    __syncthreads();
    if (tid == 0) {
        int bid = token_ids[n] & (NE - 1);
        float best = -1e30f; int bi = 0;
        for (int e = 0; e < NE; e++) {
            float lg = (e == bid ? 10.f : 0.f);
            for (int j = 0; j < 32; j++) lg += red2[j][e];
            if (lg > best) { best = lg; bi = e; }
        }
        expert_id[n] = bi;
        atomicAdd(&counts[bi], 1);
    }

    float ssq = 0.f;
    float h1v[4];
    #pragma unroll
    for (int i = 0; i < 4; i++) {
        int c = tid + i * 256;
        float coa = co[(long)n * 3072 + c];
        float cob = co[(long)n * 3072 + DM + c];
        float cog = co[(long)n * 3072 + 2 * DM + c];
        float alpha = 1.f / (1.f + __expf(-coa));
        float sp = (cob > 20.f) ? cob : log1pf(__expf(cob));
        float beta = fminf(sp, 2.0f);
        float gate = 1.f / (1.f + __expf(-cog));
        float ov = o_f[(long)n * DM + c];
        float vv = velocity[(long)n * DM + c];
        float err = ov - mu_s[c];
        float vn = fminf(fmaxf(alpha * vv - beta * err, -10.f), 10.f);
        float hn = ov + 0.1f * gate * vn;
        float h1 = hidden_in[(long)n * DM + c] + hn;
        h1v[i] = h1;
        ssq += h1 * h1;
        out_vnext[(long)n * DM + c] = vn;
        out_mu[(long)n * DM + c] = mu_s[c];
        out0[(long)n * DM + c] = h1;     // pre-MoE residual; k_red_down adds y
    }
    float tot = blockReduceSum256(ssq);
    float rstd = rsqrtf(tot / (float)DM + 1e-6f);
    #pragma unroll
    for (int i = 0; i < 4; i++) {
        int c = tid + i * 256;
        x_bf[(long)n * DM + c] = f2b(h1v[i] * rstd * ln2_w[c]);
    }
}

// ---------------- MoE scatter + gather, fused (offsets from counts) --------
__global__ __launch_bounds__(256) void k_scatter_gather(
    const int* __restrict__ expert_id, const int* __restrict__ counts,
    int* __restrict__ fill, int* __restrict__ perm,
    const bf16* __restrict__ x, bf16* __restrict__ xg)
{
    int n = blockIdx.x * 4 + (threadIdx.x >> 6);
    int lane = threadIdx.x & 63;
    int e = expert_id[n];
    int p = 0;
    if (lane == 0) {
        int off = 0;
        #pragma unroll
        for (int i = 0; i < NE; i++) off += (i < e) ? counts[i] : 0;
        p = off + atomicAdd(&fill[e], 1);
        perm[p] = n;
    }
    p = __shfl(p, 0, 64);
    const int4* s = (const int4*)(x + (long)n * DM);
    int4* d = (int4*)(xg + (long)p * DM);
    d[lane] = s[lane];
    d[lane + 64] = s[lane + 64];
}

__global__ __launch_bounds__(256) void k_silumul(const bf16* __restrict__ gu,
                                                 bf16* __restrict__ mid) {
    long i = ((long)blockIdx.x * 256 + threadIdx.x) * 8;   // over 2048*2048
    long r = i >> 11, c = i & 2047;
    short8 g8 = *(const short8*)(gu + r * 4096 + c);
    short8 u8 = *(const short8*)(gu + r * 4096 + 2048 + c);
    short8 o;
    #pragma unroll
    for (int j = 0; j < 8; j++) {
        short gs = g8[j], us = u8[j];
        float g = b2f(*(bf16*)&gs);
        float u = b2f(*(bf16*)&us);
        o[j] = f2s(g / (1.f + __expf(-g)) * u);
    }
    *(short8*)(mid + i) = o;
}

// ---------------- launcher ----------------
extern "C" void kernel_launch(void* const* d_in, const int* in_sizes, int n_in,
                              void* d_out, int out_size, void* d_ws, size_t ws_size,
                              hipStream_t stream) {
    (void)in_sizes; (void)n_in; (void)out_size; (void)ws_size;
    const float* hidden     = (const float*)d_in[0];
    const int*   positions  = (const int*)d_in[1];
    const float* velocity   = (const float*)d_in[2];
    const int*   token_ids  = (const int*)d_in[3];
    const float* mu_prev    = (const float*)d_in[4];
    const float* ln1_w      = (const float*)d_in[5];
    const float* ln2_w      = (const float*)d_in[6];
    const float* wq         = (const float*)d_in[7];
    const float* wk         = (const float*)d_in[8];
    const float* wv         = (const float*)d_in[9];
    const float* wo         = (const float*)d_in[10];
    const float* w_mu_q     = (const float*)d_in[11];
    const float* w_mu_k     = (const float*)d_in[12];
    const float* w_mu_v     = (const float*)d_in[13];
    const float* qnorm_w    = (const float*)d_in[14];
    const float* knorm_w    = (const float*)d_in[15];
    const float* dyn_mu     = (const float*)d_in[16];
    const float* dyn_proj   = (const float*)d_in[17];
    const float* ctrl_in_w  = (const float*)d_in[18];
    const float* ctrl_in_b  = (const float*)d_in[19];
    const float* ctrl_out_w = (const float*)d_in[20];
    const float* ctrl_out_b = (const float*)d_in[21];
    const float* mu_router  = (const float*)d_in[22];
    const float* w_gate     = (const float*)d_in[23];
    const float* w_up       = (const float*)d_in[24];
    const float* w_down     = (const float*)d_in[25];

    float* out0 = (float*)d_out;
    float* out1 = out0 + (long)N_TOK * DM;
    float* out2 = out1 + (long)N_TOK * DM;

    char* p = (char*)d_ws;
    auto alloc = [&](size_t bytes) -> void* {
        void* r = (void*)p;
        p += (bytes + 255) & ~(size_t)255;
        return r;
    };
    bf16* WqkvT   = (bf16*)alloc((long)1536 * 2048 * 2);
    bf16* woT     = (bf16*)alloc((long)1024 * 1024 * 2);
    bf16* dynT    = (bf16*)alloc((long)1024 * 1024 * 2);
    bf16* ctrlinT = (bf16*)alloc((long)64 * 2048 * 2);
    bf16* ctrloutT= (bf16*)alloc((long)3072 * 64 * 2);
    bf16*  catA   = (bf16*)alloc((long)N_TOK * 2048 * 2);  // [h|mu_prev]; attn_bf alias
    bf16*  ctrlA  = (bf16*)alloc((long)N_TOK * 2048 * 2);  // [o_bf|vel_bf]
    float* xbuf   = (float*)alloc((long)N_TOK * 1536 * 4); // x_bf/xg_bf/ctrl-part
    bf16*  q_bf   = (bf16*)alloc((long)N_TOK * NH * DH * 2);
    bf16*  k_bf   = (bf16*)alloc((long)N_TOK * NKV * DH * 2);
    bf16*  v_bf   = (bf16*)alloc((long)N_TOK * NKV * DH * 2);
    bf16*  vt_bf  = (bf16*)alloc((long)NKV * DH * N_TOK * 2);
    float* o_f    = (float*)alloc((long)N_TOK * DM * 4);   // mid_bf alias
    float* coGu   = (float*)alloc((long)N_TOK * 3072 * 4); // ml / co / gu_bf
    float* splitb = (float*)alloc((long)4 * N_TOK * DM * 4); // split-K partials / opart
    bf16*  ctrlbf = (bf16*)alloc((long)N_TOK * CH * 2);
    int*   expert_id = (int*)alloc(N_TOK * 4);
    int*   perm      = (int*)alloc(N_TOK * 4);
    int*   counts    = (int*)alloc(64 * 4);
    int*   fill      = (int*)alloc(64 * 4);

    bf16*  attn_bf = catA;
    bf16*  x_bf    = (bf16*)xbuf;
    bf16*  xg_bf   = (bf16*)xbuf + (long)N_TOK * DM;
    float* cpart   = (float*)((bf16*)xbuf + (long)2 * N_TOK * DM);  // 8*2048*64 fp32
    float* opart   = splitb;                                // 4*2048*1024 fp32 (32 MB)
    float2* ml     = (float2*)coGu;                         // 1 MB; dead after merge
    float* co_f    = coGu;
    bf16*  gu_bf   = (bf16*)coGu;
    bf16*  mid_bf  = (bf16*)o_f;

    dim3 blk(256);

    // ---- small-weight transposes only (TK=256 main + TK=64 for ctrl_out) --
    TTab tt{};
    int st = 0;
    auto ent = [&](int i, const float* s, bf16* d, long ss, long ds,
                   int sN, int ldk, int tN, int tK, int nE) {
        tt.t[i].src = s; tt.t[i].dst = d;
        tt.t[i].sstride = ss; tt.t[i].dstride = ds;
        tt.t[i].sN = sN; tt.t[i].ldk = ldk;
        tt.t[i].tN = tN; tt.t[i].tilesPer = tN * tK;
        tt.t[i].start = st;
        st += tN * tK * nE;
    };
    ent(0,  wq,         WqkvT,                          0, 0, 1024, 2048, 16, 4, 1);
    ent(1,  wk,         WqkvT + (long)1024 * 2048,      0, 0, 256,  2048,  4, 4, 1);
    ent(2,  wv,         WqkvT + (long)1280 * 2048,      0, 0, 256,  2048,  4, 4, 1);
    ent(3,  w_mu_q,     WqkvT + 1024,                   0, 0, 1024, 2048, 16, 4, 1);
    ent(4,  w_mu_k,     WqkvT + (long)1024 * 2048 + 1024, 0, 0, 256, 2048, 4, 4, 1);
    ent(5,  w_mu_v,     WqkvT + (long)1280 * 2048 + 1024, 0, 0, 256, 2048, 4, 4, 1);
    ent(6,  wo,         woT,                            0, 0, 1024, 1024, 16, 4, 1);
    ent(7,  dyn_proj,   dynT,                           0, 0, 1024, 1024, 16, 4, 1);
    ent(8,  ctrl_in_w,  ctrlinT,                        0, 0, 64,   2048,  1, 8, 1);
    int stMain = st;
    ent(9,  ctrl_out_w, ctrloutT,                       0, 0, 3072, 64,   48, 1, 1);
    tt.t[10].start = 0x7fffffff;
    tt.t[11].start = 0x7fffffff;
    tt.t[12].start = 0x7fffffff;
    k_transpose_all<256><<<stMain, blk, 0, stream>>>(tt, 0, counts, fill);
    k_transpose_all<64><<<st - stMain, blk, 0, stream>>>(tt, stMain, counts, fill);

    // ---- activation prep (rmsnorm + 2 casts fused) ----
    k_prep<<<N_TOK, blk, 0, stream>>>(hidden, ln1_w, mu_prev, velocity, catA, ctrlA);

    // ---- QKV: [h|mu] @ [Wqkv; Wmu]  split-K2 -> partials in splitb ----
    k_gemm<<<dim3(12,16,2), blk, 0, stream>>>(catA, 2048, WqkvT, 2048, 0,
        splitb, 1536, nullptr, nullptr, 0, 2048, 0, 2, (long)N_TOK * 1536,
        nullptr);

    k_qkv_post<<<N_TOK, blk, 0, stream>>>(splitb, positions, qnorm_w, knorm_w, q_bf, k_bf, v_bf);
    k_vt<<<dim3(32,1,NKV), blk, 0, stream>>>(v_bf, vt_bf);
    k_attn<<<dim3(32,16,4), blk, 0, stream>>>(q_bf, k_bf, vt_bf, opart, ml);
    k_attn_merge<<<N_TOK, blk, 0, stream>>>(opart, ml, attn_bf);

    // ---- o = attn @ wo  split-K2; reduce -> o_f fp32 + ctrlA bf16 ----
    k_gemm<<<dim3(8,16,2), blk, 0, stream>>>(attn_bf, 1024, woT, 1024, 0,
        splitb, 1024, nullptr, nullptr, 0, 1024, 0, 2, (long)N_TOK * DM,
        nullptr);
    k_red_wo<<<N_TOK, blk, 0, stream>>>(splitb, o_f, ctrlA);

    // ---- mu = dyn_mu + o @ dyn_proj  split-K2 (summed inside k_ode) ----
    k_gemm<<<dim3(8,16,2), blk, 0, stream>>>(ctrlA, 2048, dynT, 1024, 0,
        splitb, 1024, nullptr, nullptr, 0, 1024, 0, 2, (long)N_TOK * DM,
        nullptr);

    // ---- ctrl chain ----
    k_ctrl_gemm<<<dim3(16,8,1), blk, 0, stream>>>(ctrlA, ctrlinT, cpart);
    k_silu_ctrl<<<(N_TOK * CH) / 1024, blk, 0, stream>>>(cpart, ctrl_in_b, ctrlbf);
    k_gemm<<<dim3(24,16,1), blk, 0, stream>>>(ctrlbf, 64, ctrloutT, 64, 0,
        co_f, 3072, ctrl_out_b, nullptr, 0, 64, GEMM_WRITE | GEMM_BIAS, 1, 0,
        nullptr);

    k_ode<<<N_TOK, blk, 0, stream>>>(co_f, o_f, velocity, splitb, dyn_mu, hidden,
        mu_router, token_ids, ln2_w, out0, out1, out2, x_bf, expert_id, counts);

    k_scatter_gather<<<N_TOK / 4, blk, 0, stream>>>(expert_id, counts, fill, perm,
        x_bf, xg_bf);

    // ---- MoE: gate/up/down consume fp32 weights directly (no transpose) ---
    k_gemm_f32b<<<dim3(32,16,NE), blk, 0, stream>>>(xg_bf, 1024,
        w_gate, w_up, 2048, (long)1024 * 2048, 2048,
        nullptr, 0, gu_bf, 4096, 1024, GEMM_WRITEB, 1, 0, counts);
    k_silumul<<<(N_TOK * FF) / (256 * 8), blk, 0, stream>>>(gu_bf, mid_bf);
    k_gemm_f32b<<<dim3(8,16,NE*4), blk, 0, stream>>>(mid_bf, 2048,
        w_down, w_down, 1024, (long)2048 * 1024, 1 << 30,
        splitb, 1024, nullptr, 0, 2048, 0, 4, (long)N_TOK * DM, counts);
    k_red_down<<<N_TOK, blk, 0, stream>>>(splitb, perm, out0);
}